// Round 8
// baseline (3784.717 us; speedup 1.0000x reference)
//
#include <hip/hip_runtime.h>

// ---------------------------------------------------------------------------
// TransMIL forward. Round 8: fix gemm_bf16x3 scratch spills (r7 counters:
// WRITE 874MB vs 102MB ideal, VGPR=76 vs ~160 needed => spill-to-scratch).
// Changes: __launch_bounds__(256,1); per-m A-frag liveness; XCD block swizzle.
// Staging/swizzle/MFMA paths byte-identical to the absmax=0.0-verified r7.
// Dims: B=1, N=16384 -> Hs=Ws=128, tokens=16385, D=512, DIN=1024, HEADS=8,
// DH=64, M=256 landmarks, pad=255, npd=16640, l=65.
// ---------------------------------------------------------------------------

#define NTOK   16385
#define NPD    16640
#define PADR   255
#define NCHUNK 10          // flash a3v key chunks
#define KT_A3  26          // 26 tiles * 64 keys per chunk; 10*26*64=16640
#define SCL    0.125f      // DH^-0.5

typedef __attribute__((ext_vector_type(8))) short bf16x8_t;
typedef __attribute__((ext_vector_type(4))) float f32x4_t;

__device__ __forceinline__ ushort f2bf(float f) {
    uint u = __float_as_uint(f);
    u += 0x7fff + ((u >> 16) & 1);          // round-to-nearest-even
    return (ushort)(u >> 16);
}
__device__ __forceinline__ float bf2f(ushort h) {
    return __uint_as_float((uint)h << 16);
}

__device__ __forceinline__ void fma44(float (&o)[4], const float4 a,
                                      const float4 b0, const float4 b1,
                                      const float4 b2, const float4 b3)
{
    o[0] = fmaf(a.x,b0.x, fmaf(a.y,b1.x, fmaf(a.z,b2.x, fmaf(a.w,b3.x, o[0]))));
    o[1] = fmaf(a.x,b0.y, fmaf(a.y,b1.y, fmaf(a.z,b2.y, fmaf(a.w,b3.y, o[1]))));
    o[2] = fmaf(a.x,b0.z, fmaf(a.y,b1.z, fmaf(a.z,b2.z, fmaf(a.w,b3.z, o[2]))));
    o[3] = fmaf(a.x,b0.w, fmaf(a.y,b1.w, fmaf(a.z,b2.w, fmaf(a.w,b3.w, o[3]))));
}

// ---------------------------------------------------------------------------
// split fp32 -> bf16 hi/lo, 8 elems/thread, grid-stride
// ---------------------------------------------------------------------------
__global__ __launch_bounds__(256)
void cvt_split(const float* __restrict__ in, ushort* __restrict__ hi,
               ushort* __restrict__ lo, long n8)
{
    for (long i = (long)blockIdx.x * 256 + threadIdx.x; i < n8;
         i += (long)gridDim.x * 256) {
        float4 a = *(const float4*)(in + i * 8);
        float4 b = *(const float4*)(in + i * 8 + 4);
        float v[8] = {a.x, a.y, a.z, a.w, b.x, b.y, b.z, b.w};
        ushort h[8], l[8];
        #pragma unroll
        for (int j = 0; j < 8; ++j) {
            h[j] = f2bf(v[j]);
            l[j] = f2bf(v[j] - bf2f(h[j]));
        }
        uint4 hv = make_uint4((uint)h[0] | ((uint)h[1] << 16),
                              (uint)h[2] | ((uint)h[3] << 16),
                              (uint)h[4] | ((uint)h[5] << 16),
                              (uint)h[6] | ((uint)h[7] << 16));
        uint4 lv = make_uint4((uint)l[0] | ((uint)l[1] << 16),
                              (uint)l[2] | ((uint)l[3] << 16),
                              (uint)l[4] | ((uint)l[5] << 16),
                              (uint)l[6] | ((uint)l[7] << 16));
        *(uint4*)(hi + i * 8) = hv;
        *(uint4*)(lo + i * 8) = lv;
    }
}

// ---------------------------------------------------------------------------
// bf16x3 split GEMM: C(MxN) = (Ah+Al)(M x K) @ ((Bh+Bl)(N x K))^T  (3 MFMA terms)
// 128x128 tile, 4 waves, BK=32, XOR-swizzled LDS, next-tile reg prefetch.
// launch_bounds(256,1): loosest VGPR constraint -- r7's default spilled the
// K-loop working set to scratch (874MB writes vs 102MB C).
// m204 bijective XCD swizzle on the linearized grid (valid for any nwg).
// ---------------------------------------------------------------------------
template<bool RELU, bool BIAS, bool ACCUM>
__global__ __launch_bounds__(256, 1)
void gemm_bf16x3(const ushort* __restrict__ Ah, const ushort* __restrict__ Al, int lda,
                 const ushort* __restrict__ Bh, const ushort* __restrict__ Bl, int ldb,
                 const float* __restrict__ bias, float* __restrict__ C, int ldc,
                 int M, int K)
{
    __shared__ __align__(16) ushort sAh[4096], sAl[4096], sBh[4096], sBl[4096];
    const int t = threadIdx.x;
    const int lane = t & 63, w = t >> 6;
    const int wr = (w >> 1) << 6, wc = (w & 1) << 6;

    // XCD-aware bijective remap (m204): consecutive remapped ids share an XCD.
    const int nwg = gridDim.x * gridDim.y;
    int bid = blockIdx.x + blockIdx.y * gridDim.x;
    {
        int q = nwg >> 3, r = nwg & 7;
        int xcd = bid & 7, rank = bid >> 3;
        bid = (xcd < r ? xcd * (q + 1) : r * (q + 1) + (xcd - r) * q) + rank;
    }
    const int m0 = (bid % gridDim.x) << 7;
    const int n0 = (bid / gridDim.x) << 7;

    const int ln15 = lane & 15, kb = lane >> 4;

    // staging: each thread owns row srow (and srow+64), k-chunk sc8 of 8 shorts
    const int srow = t >> 2, sc8 = t & 3;
    const int sidx0 = (srow << 5) + ((sc8 ^ (srow & 3)) << 3);

    uint4 ra_h[2], ra_l[2], rb_h[2], rb_l[2];
    #pragma unroll
    for (int p = 0; p < 2; ++p) {
        int row = srow + (p << 6);
        long ao = (long)(m0 + row) * lda + sc8 * 8;
        long bo = (long)(n0 + row) * ldb + sc8 * 8;
        ra_h[p] = *(const uint4*)(Ah + ao);
        ra_l[p] = *(const uint4*)(Al + ao);
        rb_h[p] = *(const uint4*)(Bh + bo);
        rb_l[p] = *(const uint4*)(Bl + bo);
    }

    f32x4_t zero4 = {0.f, 0.f, 0.f, 0.f};
    f32x4_t acc[4][4];
    #pragma unroll
    for (int m = 0; m < 4; ++m)
        #pragma unroll
        for (int n = 0; n < 4; ++n) acc[m][n] = zero4;

    int k0 = 0;
    for (;;) {
        __syncthreads();
        #pragma unroll
        for (int p = 0; p < 2; ++p) {
            int idx = sidx0 + (p << 11);
            *(uint4*)&sAh[idx] = ra_h[p];
            *(uint4*)&sAl[idx] = ra_l[p];
            *(uint4*)&sBh[idx] = rb_h[p];
            *(uint4*)&sBl[idx] = rb_l[p];
        }
        __syncthreads();
        k0 += 32;
        if (k0 < K) {
            #pragma unroll
            for (int p = 0; p < 2; ++p) {
                int row = srow + (p << 6);
                long ao = (long)(m0 + row) * lda + k0 + sc8 * 8;
                long bo = (long)(n0 + row) * ldb + k0 + sc8 * 8;
                ra_h[p] = *(const uint4*)(Ah + ao);
                ra_l[p] = *(const uint4*)(Al + ao);
                rb_h[p] = *(const uint4*)(Bh + bo);
                rb_l[p] = *(const uint4*)(Bl + bo);
            }
        }
        // B-fragments for all 4 column tiles (32 VGPRs live) ...
        bf16x8_t bh[4], bl[4];
        #pragma unroll
        for (int n = 0; n < 4; ++n) {
            int row = wc + (n << 4) + ln15;
            int idx = (row << 5) + ((kb ^ (row & 3)) << 3);
            bh[n] = *(const bf16x8_t*)&sBh[idx];
            bl[n] = *(const bf16x8_t*)&sBl[idx];
        }
        // ... A-fragments loaded per-m (8 VGPRs live at a time)
        #pragma unroll
        for (int m = 0; m < 4; ++m) {
            int row = wr + (m << 4) + ln15;
            int idx = (row << 5) + ((kb ^ (row & 3)) << 3);
            bf16x8_t ahm = *(const bf16x8_t*)&sAh[idx];
            bf16x8_t alm = *(const bf16x8_t*)&sAl[idx];
            #pragma unroll
            for (int n = 0; n < 4; ++n) {
                acc[m][n] = __builtin_amdgcn_mfma_f32_16x16x32_bf16(alm, bh[n], acc[m][n], 0, 0, 0);
                acc[m][n] = __builtin_amdgcn_mfma_f32_16x16x32_bf16(ahm, bl[n], acc[m][n], 0, 0, 0);
                acc[m][n] = __builtin_amdgcn_mfma_f32_16x16x32_bf16(ahm, bh[n], acc[m][n], 0, 0, 0);
            }
        }
        if (k0 >= K) break;
    }

    // D layout: row = kb*4 + reg, col = ln15 within each 16x16 fragment
    #pragma unroll
    for (int m = 0; m < 4; ++m) {
        #pragma unroll
        for (int r = 0; r < 4; ++r) {
            int gr = m0 + wr + (m << 4) + (kb << 2) + r;
            if (gr >= M) continue;
            #pragma unroll
            for (int n = 0; n < 4; ++n) {
                int gc = n0 + wc + (n << 4) + ln15;
                float v = acc[m][n][r];
                if (BIAS) v += bias[gc];
                if (RELU) v = fmaxf(v, 0.f);
                float* cp = C + (long)gr * ldc + gc;
                if (ACCUM) *cp += v; else *cp = v;
            }
        }
    }
}

// ---------------------------------------------------------------------------
// Batched small GEMM (pinv etc): C = c0*A + c1*(A@B or A@B^T)   [fp32]
// ---------------------------------------------------------------------------
template<bool TRANSB>
__global__ __launch_bounds__(256)
void bgemm(const float* A0, long aB, const float* B0, long bB,
           float* __restrict__ C0, long cB, int N, int K, float c0, float c1)
{
    __shared__ float As[64][36];
    __shared__ float Bs[32][68];
    const int t = threadIdx.x, tx = t & 15, ty = t >> 4;
    const int tx4 = tx * 4, ty4 = ty * 4;
    const int m0 = blockIdx.x * 64, n0 = blockIdx.y * 64;
    const float* A = A0 + blockIdx.z * aB;
    const float* B = B0 + blockIdx.z * bB;
    float* C = C0 + blockIdx.z * cB;
    float acc[4][4] = {};
    for (int k0 = 0; k0 < K; k0 += 32) {
        __syncthreads();
        #pragma unroll
        for (int qq = 0; qq < 2; ++qq) {
            int q4 = t + qq * 256;
            int r = q4 >> 3, c4 = (q4 & 7) << 2;
            *(float4*)&As[r][c4] = *(const float4*)(A + (long)(m0 + r) * K + k0 + c4);
        }
        if (!TRANSB) {
            #pragma unroll
            for (int qq = 0; qq < 2; ++qq) {
                int q4 = t + qq * 256;
                int r = q4 >> 4, c4 = (q4 & 15) << 2;
                *(float4*)&Bs[r][c4] = *(const float4*)(B + (long)(k0 + r) * N + n0 + c4);
            }
        } else {
            #pragma unroll
            for (int qq = 0; qq < 2; ++qq) {
                int q4 = t + qq * 256;
                int n = q4 >> 3, c4 = (q4 & 7) << 2;
                float4 bv = *(const float4*)(B + (long)(n0 + n) * K + k0 + c4);
                Bs[c4 + 0][n] = bv.x; Bs[c4 + 1][n] = bv.y;
                Bs[c4 + 2][n] = bv.z; Bs[c4 + 3][n] = bv.w;
            }
        }
        __syncthreads();
        #pragma unroll
        for (int kq = 0; kq < 32; kq += 4) {
            float4 a0 = *(const float4*)&As[ty4 + 0][kq];
            float4 a1 = *(const float4*)&As[ty4 + 1][kq];
            float4 a2 = *(const float4*)&As[ty4 + 2][kq];
            float4 a3 = *(const float4*)&As[ty4 + 3][kq];
            float4 b0 = *(const float4*)&Bs[kq + 0][tx4];
            float4 b1 = *(const float4*)&Bs[kq + 1][tx4];
            float4 b2 = *(const float4*)&Bs[kq + 2][tx4];
            float4 b3 = *(const float4*)&Bs[kq + 3][tx4];
            fma44(acc[0], a0, b0, b1, b2, b3);
            fma44(acc[1], a1, b0, b1, b2, b3);
            fma44(acc[2], a2, b0, b1, b2, b3);
            fma44(acc[3], a3, b0, b1, b2, b3);
        }
    }
    #pragma unroll
    for (int i = 0; i < 4; ++i) {
        #pragma unroll
        for (int j = 0; j < 4; ++j) {
            float val = c1 * acc[i][j];
            if (c0 != 0.f)
                val += c0 * A[(long)(m0 + ty4 + i) * K + (n0 + tx4 + j)];
            C[(long)(m0 + ty4 + i) * N + n0 + tx4 + j] = val;
        }
    }
}

// ---------------------------------------------------------------------------
// Flash-style fused softmax(scale * Q@K^T) @ V, 64x64 tiles, fp32.
// ---------------------------------------------------------------------------
template<bool PARTIAL>
__global__ __launch_bounds__(256)
void flash_kernel(const float* __restrict__ qb, long q_rs, long q_hs,
                  const float* __restrict__ kb, long k_rs, long k_hs,
                  const float* __restrict__ vb, long v_rs, long v_hs,
                  float* __restrict__ ob, long o_rs, long o_hs,
                  float* __restrict__ pm, float* __restrict__ pl,
                  float* __restrict__ pacc, int ktiles, float scale)
{
    __shared__ float qs[64][68];
    __shared__ float kps[64][68];
    __shared__ float vs[64][68];
    const int t = threadIdx.x, tx = t & 15, ty = t >> 4;
    const int tx4 = tx * 4, ty4 = ty * 4;
    const int qt = blockIdx.x, h = blockIdx.y, ch = blockIdx.z;

    const float* q = qb + (long)h * q_hs + (long)(qt * 64) * q_rs;
    const float* k = kb + (long)h * k_hs + (long)(ch * ktiles * 64) * k_rs;
    const float* v = vb + (long)h * v_hs + (long)(ch * ktiles * 64) * v_rs;

    for (int q4 = t; q4 < 1024; q4 += 256) {
        int r = q4 >> 4, c4 = (q4 & 15) << 2;
        float4 val = *(const float4*)(q + (long)r * q_rs + c4);
        val.x *= scale; val.y *= scale; val.z *= scale; val.w *= scale;
        *(float4*)&qs[r][c4] = val;
    }

    float m_r[4], l_r[4], acc[4][4];
    #pragma unroll
    for (int i = 0; i < 4; ++i) {
        m_r[i] = -3.0e30f; l_r[i] = 0.f;
        acc[i][0] = acc[i][1] = acc[i][2] = acc[i][3] = 0.f;
    }

    for (int kt = 0; kt < ktiles; ++kt) {
        __syncthreads();
        for (int q4 = t; q4 < 1024; q4 += 256) {
            int r = q4 >> 4, c4 = (q4 & 15) << 2;
            float4 kv = *(const float4*)(k + (long)(kt * 64 + r) * k_rs + c4);
            kps[c4 + 0][r] = kv.x; kps[c4 + 1][r] = kv.y;
            kps[c4 + 2][r] = kv.z; kps[c4 + 3][r] = kv.w;
            *(float4*)&vs[r][c4] = *(const float4*)(v + (long)(kt * 64 + r) * v_rs + c4);
        }
        __syncthreads();
        float s[4][4] = {};
        #pragma unroll
        for (int kk = 0; kk < 64; kk += 4) {
            float4 a0 = *(const float4*)&qs[ty4 + 0][kk];
            float4 a1 = *(const float4*)&qs[ty4 + 1][kk];
            float4 a2 = *(const float4*)&qs[ty4 + 2][kk];
            float4 a3 = *(const float4*)&qs[ty4 + 3][kk];
            float4 b0 = *(const float4*)&kps[kk + 0][tx4];
            float4 b1 = *(const float4*)&kps[kk + 1][tx4];
            float4 b2 = *(const float4*)&kps[kk + 2][tx4];
            float4 b3 = *(const float4*)&kps[kk + 3][tx4];
            fma44(s[0], a0, b0, b1, b2, b3);
            fma44(s[1], a1, b0, b1, b2, b3);
            fma44(s[2], a2, b0, b1, b2, b3);
            fma44(s[3], a3, b0, b1, b2, b3);
        }
        float p[4][4];
        #pragma unroll
        for (int i = 0; i < 4; ++i) {
            float rm = fmaxf(fmaxf(s[i][0], s[i][1]), fmaxf(s[i][2], s[i][3]));
            rm = fmaxf(rm, __shfl_xor(rm, 1));
            rm = fmaxf(rm, __shfl_xor(rm, 2));
            rm = fmaxf(rm, __shfl_xor(rm, 4));
            rm = fmaxf(rm, __shfl_xor(rm, 8));
            float mn = fmaxf(m_r[i], rm);
            float corr = __expf(m_r[i] - mn);
            m_r[i] = mn;
            float rs = 0.f;
            #pragma unroll
            for (int j = 0; j < 4; ++j) { p[i][j] = __expf(s[i][j] - mn); rs += p[i][j]; }
            rs += __shfl_xor(rs, 1);
            rs += __shfl_xor(rs, 2);
            rs += __shfl_xor(rs, 4);
            rs += __shfl_xor(rs, 8);
            l_r[i] = l_r[i] * corr + rs;
            acc[i][0] *= corr; acc[i][1] *= corr; acc[i][2] *= corr; acc[i][3] *= corr;
        }
        __syncthreads();
        #pragma unroll
        for (int i = 0; i < 4; ++i)
            *(float4*)&kps[ty4 + i][tx4] = make_float4(p[i][0], p[i][1], p[i][2], p[i][3]);
        __syncthreads();
        #pragma unroll
        for (int nn = 0; nn < 64; nn += 4) {
            float4 a0 = *(const float4*)&kps[ty4 + 0][nn];
            float4 a1 = *(const float4*)&kps[ty4 + 1][nn];
            float4 a2 = *(const float4*)&kps[ty4 + 2][nn];
            float4 a3 = *(const float4*)&kps[ty4 + 3][nn];
            float4 b0 = *(const float4*)&vs[nn + 0][tx4];
            float4 b1 = *(const float4*)&vs[nn + 1][tx4];
            float4 b2 = *(const float4*)&vs[nn + 2][tx4];
            float4 b3 = *(const float4*)&vs[nn + 3][tx4];
            fma44(acc[0], a0, b0, b1, b2, b3);
            fma44(acc[1], a1, b0, b1, b2, b3);
            fma44(acc[2], a2, b0, b1, b2, b3);
            fma44(acc[3], a3, b0, b1, b2, b3);
        }
    }

    if (PARTIAL) {
        const int pidx = (h * gridDim.x + qt) * gridDim.z + ch;
        if (tx == 0) {
            #pragma unroll
            for (int i = 0; i < 4; ++i) {
                pm[pidx * 64 + ty4 + i] = m_r[i];
                pl[pidx * 64 + ty4 + i] = l_r[i];
            }
        }
        #pragma unroll
        for (int i = 0; i < 4; ++i)
            *(float4*)&pacc[(long)pidx * 4096 + (ty4 + i) * 64 + tx4] =
                make_float4(acc[i][0], acc[i][1], acc[i][2], acc[i][3]);
    } else {
        float* o = ob + (long)h * o_hs + (long)(qt * 64) * o_rs;
        #pragma unroll
        for (int i = 0; i < 4; ++i) {
            float inv = 1.f / l_r[i];
            *(float4*)(o + (long)(ty4 + i) * o_rs + tx4) =
                make_float4(acc[i][0] * inv, acc[i][1] * inv, acc[i][2] * inv, acc[i][3] * inv);
        }
    }
}

__global__ __launch_bounds__(256)
void combine_a3v(const float* __restrict__ pm, const float* __restrict__ pl,
                 const float* __restrict__ pacc, float* __restrict__ out3)
{
    int e = blockIdx.x * 256 + threadIdx.x;
    int d = e & 63, i = (e >> 6) & 255, h = e >> 14;
    int qt = i >> 6, r = i & 63;
    int pbase = (h * 4 + qt) * NCHUNK;
    float M = -3.0e30f;
    for (int c = 0; c < NCHUNK; ++c) M = fmaxf(M, pm[(pbase + c) * 64 + r]);
    float L = 0.f, val = 0.f;
    for (int c = 0; c < NCHUNK; ++c) {
        float w = __expf(pm[(pbase + c) * 64 + r] - M);
        L += pl[(pbase + c) * 64 + r] * w;
        val += pacc[(long)(pbase + c) * 4096 + r * 64 + d] * w;
    }
    out3[e] = val / L;
}

// ---------------------------------------------------------------------------
// LayerNorm h -> padded bf16 hi/lo (rows < PADR zeroed). grid NPD, block 256.
// ---------------------------------------------------------------------------
__global__ __launch_bounds__(256)
void ln_pad_bf16(const float* __restrict__ hin, const float* __restrict__ g,
                 const float* __restrict__ b, ushort* __restrict__ xph,
                 ushort* __restrict__ xpl)
{
    int row = blockIdx.x, t = threadIdx.x;
    if (row < PADR) {
        ((uint*)xph)[row * 256 + t] = 0;
        ((uint*)xpl)[row * 256 + t] = 0;
        return;
    }
    const float* xr = hin + (long)(row - PADR) * 512;
    float2 v = *(const float2*)&xr[t * 2];
    float s1 = v.x + v.y, s2 = v.x * v.x + v.y * v.y;
    for (int mask = 1; mask < 64; mask <<= 1) {
        s1 += __shfl_xor(s1, mask);
        s2 += __shfl_xor(s2, mask);
    }
    __shared__ float red[8];
    if ((t & 63) == 0) { red[(t >> 6) * 2] = s1; red[(t >> 6) * 2 + 1] = s2; }
    __syncthreads();
    s1 = red[0] + red[2] + red[4] + red[6];
    s2 = red[1] + red[3] + red[5] + red[7];
    float mu = s1 * (1.f / 512.f);
    float var = s2 * (1.f / 512.f) - mu * mu;
    float rstd = rsqrtf(var + 1e-5f);
    float2 gg = *(const float2*)&g[t * 2];
    float2 bb = *(const float2*)&b[t * 2];
    float ox = (v.x - mu) * rstd * gg.x + bb.x;
    float oy = (v.y - mu) * rstd * gg.y + bb.y;
    ushort hx = f2bf(ox), hy = f2bf(oy);
    ushort lx = f2bf(ox - bf2f(hx)), ly = f2bf(oy - bf2f(hy));
    ((uint*)xph)[row * 256 + t] = (uint)hx | ((uint)hy << 16);
    ((uint*)xpl)[row * 256 + t] = (uint)lx | ((uint)ly << 16);
}

// landmarks: mean over 65-token chunks of q and k. grid 2048, block 128.
__global__ __launch_bounds__(128)
void landmarks(const float* __restrict__ qkv, float* __restrict__ ql, float* __restrict__ kl)
{
    int bidx = blockIdx.x;
    int h = bidx >> 8, i = bidx & 255;
    int t = threadIdx.x, d = t & 63, which = t >> 6;
    const float* src = qkv + (which ? 512 : 0) + h * 64 + d;
    long base = (long)(i * 65) * 1536;
    float s = 0.f;
    for (int j = 0; j < 65; ++j) s += src[base + (long)j * 1536];
    float* dst = which ? kl : ql;
    dst[((h << 8) + i) * 64 + d] = s * (1.f / 65.f);
}

__global__ __launch_bounds__(256)
void softmax_rows(float* __restrict__ x)
{
    __shared__ float red[4];
    int row = blockIdx.x, t = threadIdx.x;
    float v = x[(long)row * 256 + t];
    float m = v;
    for (int mask = 1; mask < 64; mask <<= 1) m = fmaxf(m, __shfl_xor(m, mask));
    if ((t & 63) == 0) red[t >> 6] = m;
    __syncthreads();
    m = fmaxf(fmaxf(red[0], red[1]), fmaxf(red[2], red[3]));
    float p = __expf(v - m);
    float s = p;
    for (int mask = 1; mask < 64; mask <<= 1) s += __shfl_xor(s, mask);
    __syncthreads();
    if ((t & 63) == 0) red[t >> 6] = s;
    __syncthreads();
    s = red[0] + red[1] + red[2] + red[3];
    x[(long)row * 256 + t] = p / s;
}

__global__ __launch_bounds__(256)
void rowcolmax(const float* __restrict__ a2, float* __restrict__ red16)
{
    int h = blockIdx.x, t = threadIdx.x;
    const float* A = a2 + (long)h * 65536;
    float cs = 0.f, rs = 0.f;
    for (int i = 0; i < 256; ++i) cs += fabsf(A[i * 256 + t]);
    for (int j = 0; j < 256; ++j) rs += fabsf(A[t * 256 + j]);
    for (int mask = 1; mask < 64; mask <<= 1) {
        cs = fmaxf(cs, __shfl_xor(cs, mask));
        rs = fmaxf(rs, __shfl_xor(rs, mask));
    }
    __shared__ float red[8];
    if ((t & 63) == 0) { red[t >> 6] = rs; red[4 + (t >> 6)] = cs; }
    __syncthreads();
    if (t == 0) {
        float mr = fmaxf(fmaxf(red[0], red[1]), fmaxf(red[2], red[3]));
        float mc = fmaxf(fmaxf(red[4], red[5]), fmaxf(red[6], red[7]));
        red16[h] = mr;
        red16[8 + h] = mc;
    }
}

__global__ void pinv_scale(const float* __restrict__ red16, float* __restrict__ scal)
{
    if (threadIdx.x == 0) {
        float mr = red16[0], mc = red16[8];
        for (int i = 1; i < 8; ++i) {
            mr = fmaxf(mr, red16[i]);
            mc = fmaxf(mc, red16[8 + i]);
        }
        scal[0] = 1.f / (mr * mc);
    }
}

__global__ __launch_bounds__(256)
void ztrans(const float* __restrict__ a2, const float* __restrict__ scal, float* __restrict__ z)
{
    __shared__ float tl[64][65];
    int h = blockIdx.y, t = threadIdx.x;
    const float* A = a2 + (long)h * 65536;
    float* Z = z + (long)h * 65536;
    float s = scal[0];
    int i0 = (blockIdx.x & 3) * 64, j0 = (blockIdx.x >> 2) * 64;
    for (int q = t; q < 4096; q += 256) {
        int r = q >> 6, c = q & 63;
        tl[r][c] = A[(i0 + r) * 256 + j0 + c];
    }
    __syncthreads();
    for (int q = t; q < 4096; q += 256) {
        int r = q >> 6, c = q & 63;
        Z[(j0 + r) * 256 + i0 + c] = tl[c][r] * s;
    }
}

__global__ __launch_bounds__(256)
void resconv(const float* __restrict__ qkv, const float* __restrict__ rw, float* __restrict__ attn)
{
    int n = PADR + blockIdx.x;
    int c = blockIdx.y * 256 + threadIdx.x;
    int h = c >> 6;
    float s = 0.f;
    #pragma unroll
    for (int tt = 0; tt < 33; ++tt) {
        int m = n + tt - 16;
        if (m >= 0 && m < NPD) s += qkv[(long)m * 1536 + 1024 + c] * rw[h * 33 + tt];
    }
    attn[(long)n * 512 + c] += s;
}

__global__ void cls_copy(const float* __restrict__ cls, float* __restrict__ h)
{
    h[threadIdx.x] = cls[threadIdx.x];
}

__global__ __launch_bounds__(256)
void transpose_nc_cn(const float* __restrict__ h, float* __restrict__ f)
{
    __shared__ float tl[32][33];
    int p0 = blockIdx.x * 32, c0 = blockIdx.y * 32;
    int txx = threadIdx.x & 31, tyy = threadIdx.x >> 5;
    #pragma unroll
    for (int k = 0; k < 4; ++k) {
        int r = tyy * 4 + k;
        tl[r][txx] = h[(long)(1 + p0 + r) * 512 + c0 + txx];
    }
    __syncthreads();
    #pragma unroll
    for (int k = 0; k < 4; ++k) {
        int r = tyy * 4 + k;
        f[(long)(c0 + r) * 16384 + p0 + txx] = tl[txx][r];
    }
}

__global__ __launch_bounds__(256)
void transpose_cn_nc(const float* __restrict__ g, float* __restrict__ h)
{
    __shared__ float tl[32][33];
    int p0 = blockIdx.x * 32, c0 = blockIdx.y * 32;
    int txx = threadIdx.x & 31, tyy = threadIdx.x >> 5;
    #pragma unroll
    for (int k = 0; k < 4; ++k) {
        int r = tyy * 4 + k;
        tl[r][txx] = g[(long)(c0 + r) * 16384 + p0 + txx];
    }
    __syncthreads();
    #pragma unroll
    for (int k = 0; k < 4; ++k) {
        int r = tyy * 4 + k;
        h[(long)(1 + p0 + r) * 512 + c0 + txx] = tl[txx][r];
    }
}

__global__ __launch_bounds__(128)
void ppeg_conv(const float* __restrict__ fin, float* __restrict__ fout,
               const float* __restrict__ w7, const float* __restrict__ b7,
               const float* __restrict__ w5, const float* __restrict__ b5,
               const float* __restrict__ w3, const float* __restrict__ b3)
{
    int y = blockIdx.x, c = blockIdx.y;
    int x = threadIdx.x;
    __shared__ float ld[7][134];
    const float* base = fin + (long)c * 16384;
    #pragma unroll
    for (int ry = 0; ry < 7; ++ry) {
        int row = y + ry - 3;
        ld[ry][3 + x] = (row >= 0 && row < 128) ? base[row * 128 + x] : 0.f;
    }
    if (x < 3) {
        #pragma unroll
        for (int ry = 0; ry < 7; ++ry) { ld[ry][x] = 0.f; ld[ry][131 + x] = 0.f; }
    }
    __syncthreads();
    float acc = ld[3][3 + x] + b7[c] + b5[c] + b3[c];
    #pragma unroll
    for (int dy = 0; dy < 7; ++dy)
        #pragma unroll
        for (int dx = 0; dx < 7; ++dx)
            acc += ld[dy][x + dx] * w7[c * 49 + dy * 7 + dx];
    #pragma unroll
    for (int dy = 0; dy < 5; ++dy)
        #pragma unroll
        for (int dx = 0; dx < 5; ++dx)
            acc += ld[dy + 1][x + 1 + dx] * w5[c * 25 + dy * 5 + dx];
    #pragma unroll
    for (int dy = 0; dy < 3; ++dy)
        #pragma unroll
        for (int dx = 0; dx < 3; ++dx)
            acc += ld[dy + 2][x + 2 + dx] * w3[c * 9 + dy * 3 + dx];
    fout[(long)c * 16384 + y * 128 + x] = acc;
}

__global__ __launch_bounds__(256)
void final_head(const float* __restrict__ h, const float* __restrict__ g,
                const float* __restrict__ bb, const float* __restrict__ w,
                const float* __restrict__ bias, float* __restrict__ out)
{
    __shared__ float red[8];
    int t = threadIdx.x;
    float2 v = *(const float2*)&h[t * 2];
    float s1 = v.x + v.y, s2 = v.x * v.x + v.y * v.y;
    for (int mask = 1; mask < 64; mask <<= 1) {
        s1 += __shfl_xor(s1, mask);
        s2 += __shfl_xor(s2, mask);
    }
    if ((t & 63) == 0) { red[t >> 6] = s1; red[4 + (t >> 6)] = s2; }
    __syncthreads();
    s1 = red[0] + red[1] + red[2] + red[3];
    s2 = red[4] + red[5] + red[6] + red[7];
    float mu = s1 * (1.f / 512.f);
    float var = s2 * (1.f / 512.f) - mu * mu;
    float rstd = rsqrtf(var + 1e-5f);
    float2 gg = *(const float2*)&g[t * 2];
    float2 b2v = *(const float2*)&bb[t * 2];
    float o0 = (v.x - mu) * rstd * gg.x + b2v.x;
    float o1 = (v.y - mu) * rstd * gg.y + b2v.y;
    float p0 = o0 * w[t * 2] + o1 * w[t * 2 + 1];
    float p1 = o0 * w[512 + t * 2] + o1 * w[512 + t * 2 + 1];
    for (int mask = 1; mask < 64; mask <<= 1) {
        p0 += __shfl_xor(p0, mask);
        p1 += __shfl_xor(p1, mask);
    }
    __syncthreads();
    if ((t & 63) == 0) { red[t >> 6] = p0; red[4 + (t >> 6)] = p1; }
    __syncthreads();
    if (t == 0) {
        out[0] = red[0] + red[1] + red[2] + red[3] + bias[0];
        out[1] = red[4] + red[5] + red[6] + red[7] + bias[1];
    }
}

// ---------------------------------------------------------------------------
static void run_nystrom(hipStream_t stream, float* h, ushort* xph, ushort* xpl,
                        float* qkv, float* attn, float* ql, float* kl, float* a2b,
                        float* zA, float* zB, float* xzb, float* u1b, float* u2b,
                        float* out3, float* wvb, float* pm, float* pl, float* pacc,
                        float* red16, float* scal,
                        const float* ng, const float* nb,
                        const ushort* qwh, const ushort* qwl,
                        const ushort* owh, const ushort* owl,
                        const float* ob, const float* resw)
{
    ln_pad_bf16<<<NPD, 256, 0, stream>>>(h, ng, nb, xph, xpl);
    gemm_bf16x3<false, false, false><<<dim3(130, 12), 256, 0, stream>>>(
        xph, xpl, 512, qwh, qwl, 512, nullptr, qkv, 1536, NPD, 512);
    landmarks<<<2048, 128, 0, stream>>>(qkv, ql, kl);
    bgemm<true><<<dim3(4, 4, 8), 256, 0, stream>>>(ql, 16384L, kl, 16384L, a2b, 65536L,
                                                   256, 64, 0.f, SCL);
    softmax_rows<<<2048, 256, 0, stream>>>(a2b);
    rowcolmax<<<8, 256, 0, stream>>>(a2b, red16);
    pinv_scale<<<1, 64, 0, stream>>>(red16, scal);
    ztrans<<<dim3(16, 8), 256, 0, stream>>>(a2b, scal, zA);
    float* zc = zA;
    float* zn = zB;
    for (int it = 0; it < 6; ++it) {
        bgemm<false><<<dim3(4, 4, 8), 256, 0, stream>>>(a2b, 65536L, zc, 65536L, xzb, 65536L,
                                                        256, 256, 0.f, 1.f);
        bgemm<false><<<dim3(4, 4, 8), 256, 0, stream>>>(xzb, 65536L, xzb, 65536L, u1b, 65536L,
                                                        256, 256, 7.f, -1.f);
        bgemm<false><<<dim3(4, 4, 8), 256, 0, stream>>>(xzb, 65536L, u1b, 65536L, u2b, 65536L,
                                                        256, 256, 15.f, -1.f);
        bgemm<false><<<dim3(4, 4, 8), 256, 0, stream>>>(zc, 65536L, u2b, 65536L, zn, 65536L,
                                                        256, 256, 3.25f, -0.25f);
        float* tmp = zc; zc = zn; zn = tmp;
    }
    flash_kernel<true><<<dim3(4, 8, NCHUNK), 256, 0, stream>>>(
        ql, 64L, 16384L, qkv + 512, 1536L, 64L, qkv + 1024, 1536L, 64L,
        nullptr, 0L, 0L, pm, pl, pacc, KT_A3, SCL);
    combine_a3v<<<512, 256, 0, stream>>>(pm, pl, pacc, out3);
    bgemm<false><<<dim3(4, 1, 8), 256, 0, stream>>>(zc, 65536L, out3, 16384L, wvb, 16384L,
                                                    64, 256, 0.f, 1.f);
    flash_kernel<false><<<dim3(260, 8, 1), 256, 0, stream>>>(
        qkv, 1536L, 64L, kl, 64L, 16384L, wvb, 64L, 16384L,
        attn, 512L, 64L, nullptr, nullptr, nullptr, 4, SCL);
    resconv<<<dim3(16385, 2), 256, 0, stream>>>(qkv, resw, attn);
    // convert attn rows [PADR, PADR+NTOK) to bf16 hi/lo (reuse xp region)
    cvt_split<<<2048, 256, 0, stream>>>(attn + (long)PADR * 512, xph, xpl,
                                        (long)NTOK * 512 / 8);
    // h += attn_bf16 @ ow^T + ob
    gemm_bf16x3<false, true, true><<<dim3(129, 4), 256, 0, stream>>>(
        xph, xpl, 512, owh, owl, 512, ob, h, 512, NTOK, 512);
}

extern "C" void kernel_launch(void* const* d_in, const int* in_sizes, int n_in,
                              void* d_out, int out_size, void* d_ws, size_t ws_size,
                              hipStream_t stream)
{
    const float* x      = (const float*)d_in[0];
    const float* fc1w   = (const float*)d_in[1];
    const float* fc1b   = (const float*)d_in[2];
    const float* clstok = (const float*)d_in[3];
    const float* l1ng   = (const float*)d_in[4];
    const float* l1nb   = (const float*)d_in[5];
    const float* l1qkv  = (const float*)d_in[6];
    const float* l1ow   = (const float*)d_in[7];
    const float* l1ob   = (const float*)d_in[8];
    const float* l1res  = (const float*)d_in[9];
    const float* pw7    = (const float*)d_in[10];
    const float* pb7    = (const float*)d_in[11];
    const float* pw5    = (const float*)d_in[12];
    const float* pb5    = (const float*)d_in[13];
    const float* pw3    = (const float*)d_in[14];
    const float* pb3    = (const float*)d_in[15];
    const float* l2ng   = (const float*)d_in[16];
    const float* l2nb   = (const float*)d_in[17];
    const float* l2qkv  = (const float*)d_in[18];
    const float* l2ow   = (const float*)d_in[19];
    const float* l2ob   = (const float*)d_in[20];
    const float* l2res  = (const float*)d_in[21];
    const float* fng    = (const float*)d_in[22];
    const float* fnb    = (const float*)d_in[23];
    const float* fc2w   = (const float*)d_in[24];
    const float* fc2b   = (const float*)d_in[25];
    (void)in_sizes; (void)n_in; (void)out_size; (void)ws_size;
    float* out = (float*)d_out;
    float* ws = (float*)d_ws;

    size_t off = 0;
    auto alloc = [&](size_t n) { float* p = ws + off; off += n; return p; };
    float* h    = alloc((size_t)NTOK * 512);
    float* xph_f = alloc((size_t)NPD * 256);      // NPD*512 ushorts
    float* xpl_f = alloc((size_t)NPD * 256);
    float* qkv  = alloc((size_t)NPD * 1536);
    float* attn = alloc((size_t)NPD * 512);
    float* ql   = alloc(8 * 256 * 64);
    float* kl   = alloc(8 * 256 * 64);
    float* a2b  = alloc(8 * 256 * 256);
    float* zA   = alloc(8 * 256 * 256);
    float* zB   = alloc(8 * 256 * 256);
    float* xzb  = alloc(8 * 256 * 256);
    float* u1b  = alloc(8 * 256 * 256);
    float* u2b  = alloc(8 * 256 * 256);
    float* out3 = alloc(8 * 256 * 64);
    float* wvb  = alloc(8 * 256 * 64);
    float* pm   = alloc(8 * 4 * NCHUNK * 64);
    float* pl   = alloc(8 * 4 * NCHUNK * 64);
    float* pacc = alloc((size_t)8 * 4 * NCHUNK * 4096);
    float* red16 = alloc(16);
    float* scal  = alloc(4);
    // bf16 weight buffers (ushort counts halved into float words)
    ushort* fwh = (ushort*)alloc(512 * 1024 / 2);
    ushort* fwl = (ushort*)alloc(512 * 1024 / 2);
    ushort* q1h = (ushort*)alloc(1536 * 512 / 2);
    ushort* q1l = (ushort*)alloc(1536 * 512 / 2);
    ushort* q2h = (ushort*)alloc(1536 * 512 / 2);
    ushort* q2l = (ushort*)alloc(1536 * 512 / 2);
    ushort* o1h = (ushort*)alloc(512 * 512 / 2);
    ushort* o1l = (ushort*)alloc(512 * 512 / 2);
    ushort* o2h = (ushort*)alloc(512 * 512 / 2);
    ushort* o2l = (ushort*)alloc(512 * 512 / 2);

    ushort* xph = (ushort*)xph_f;
    ushort* xpl = (ushort*)xpl_f;
    // x hi/lo aliases the (not yet written) qkv region: 2*8.39M floats <= 25.5M
    ushort* xh = (ushort*)qkv;
    ushort* xl = (ushort*)(qkv + (size_t)16384 * 1024 / 2);
    float* fbuf = qkv;                      // PPEG reuses the (dead) qkv region
    float* gbuf = qkv + (size_t)NPD * 512;

    // weight conversions
    cvt_split<<<256, 256, 0, stream>>>(fc1w, fwh, fwl, 512 * 1024 / 8);
    cvt_split<<<384, 256, 0, stream>>>(l1qkv, q1h, q1l, 1536 * 512 / 8);
    cvt_split<<<384, 256, 0, stream>>>(l2qkv, q2h, q2l, 1536 * 512 / 8);
    cvt_split<<<128, 256, 0, stream>>>(l1ow, o1h, o1l, 512 * 512 / 8);
    cvt_split<<<128, 256, 0, stream>>>(l2ow, o2h, o2l, 512 * 512 / 8);
    cvt_split<<<2048, 256, 0, stream>>>(x, xh, xl, (long)16384 * 1024 / 8);

    // h[1:] = relu(x @ fc1_w^T + fc1_b); h[0] = cls_token
    gemm_bf16x3<true, true, false><<<dim3(128, 4), 256, 0, stream>>>(
        xh, xl, 1024, fwh, fwl, 1024, fc1b, h + 512, 512, 16384, 1024);
    cls_copy<<<1, 512, 0, stream>>>(clstok, h);

    run_nystrom(stream, h, xph, xpl, qkv, attn, ql, kl, a2b, zA, zB, xzb, u1b, u2b,
                out3, wvb, pm, pl, pacc, red16, scal,
                l1ng, l1nb, q1h, q1l, o1h, o1l, l1ob, l1res);

    transpose_nc_cn<<<dim3(512, 16), 256, 0, stream>>>(h, fbuf);
    ppeg_conv<<<dim3(128, 512), 128, 0, stream>>>(fbuf, gbuf, pw7, pb7, pw5, pb5, pw3, pb3);
    transpose_cn_nc<<<dim3(512, 16), 256, 0, stream>>>(gbuf, h);

    run_nystrom(stream, h, xph, xpl, qkv, attn, ql, kl, a2b, zA, zB, xzb, u1b, u2b,
                out3, wvb, pm, pl, pacc, red16, scal,
                l2ng, l2nb, q2h, q2l, o2h, o2l, l2ob, l2res);

    final_head<<<1, 256, 0, stream>>>(h, fng, fnb, fc2w, fc2b, out);
}

// Round 9
// 2970.785 us; speedup vs baseline: 1.2740x; 1.2740x over previous
//
#include <hip/hip_runtime.h>

// ---------------------------------------------------------------------------
// TransMIL forward. Round 9: gemm_bf16x3 staging via global_load_lds (direct
// global->LDS DMA, width=16). r7/r8 evidence: 772MB/dispatch anomalous writes
// = 32 dwords/thread/K-iter = the uint4 prefetch set spilled to scratch;
// launch_bounds hints didn't move VGPR_Count. This removes the staging regs
// entirely. Swizzle moved to the global SOURCE address (rule #21: linear LDS
// dest + pre-swizzled source); reader/MFMA/C-write identical to verified r7.
// Dims: B=1, N=16384 -> Hs=Ws=128, tokens=16385, D=512, DIN=1024, HEADS=8,
// DH=64, M=256 landmarks, pad=255, npd=16640, l=65.
// ---------------------------------------------------------------------------

#define NTOK   16385
#define NPD    16640
#define PADR   255
#define NCHUNK 10          // flash a3v key chunks
#define KT_A3  26          // 26 tiles * 64 keys per chunk; 10*26*64=16640
#define SCL    0.125f      // DH^-0.5

typedef __attribute__((ext_vector_type(8))) short bf16x8_t;
typedef __attribute__((ext_vector_type(4))) float f32x4_t;

__device__ __forceinline__ ushort f2bf(float f) {
    uint u = __float_as_uint(f);
    u += 0x7fff + ((u >> 16) & 1);          // round-to-nearest-even
    return (ushort)(u >> 16);
}
__device__ __forceinline__ float bf2f(ushort h) {
    return __uint_as_float((uint)h << 16);
}

// direct global->LDS DMA, 16B per lane; LDS dest = wave-uniform base + lane*16
__device__ __forceinline__ void gload16(const void* g, void* l)
{
    __builtin_amdgcn_global_load_lds(
        (const __attribute__((address_space(1))) void*)g,
        (__attribute__((address_space(3))) void*)l, 16, 0, 0);
}

__device__ __forceinline__ void fma44(float (&o)[4], const float4 a,
                                      const float4 b0, const float4 b1,
                                      const float4 b2, const float4 b3)
{
    o[0] = fmaf(a.x,b0.x, fmaf(a.y,b1.x, fmaf(a.z,b2.x, fmaf(a.w,b3.x, o[0]))));
    o[1] = fmaf(a.x,b0.y, fmaf(a.y,b1.y, fmaf(a.z,b2.y, fmaf(a.w,b3.y, o[1]))));
    o[2] = fmaf(a.x,b0.z, fmaf(a.y,b1.z, fmaf(a.z,b2.z, fmaf(a.w,b3.z, o[2]))));
    o[3] = fmaf(a.x,b0.w, fmaf(a.y,b1.w, fmaf(a.z,b2.w, fmaf(a.w,b3.w, o[3]))));
}

// ---------------------------------------------------------------------------
// split fp32 -> bf16 hi/lo, 8 elems/thread, grid-stride
// ---------------------------------------------------------------------------
__global__ __launch_bounds__(256)
void cvt_split(const float* __restrict__ in, ushort* __restrict__ hi,
               ushort* __restrict__ lo, long n8)
{
    for (long i = (long)blockIdx.x * 256 + threadIdx.x; i < n8;
         i += (long)gridDim.x * 256) {
        float4 a = *(const float4*)(in + i * 8);
        float4 b = *(const float4*)(in + i * 8 + 4);
        float v[8] = {a.x, a.y, a.z, a.w, b.x, b.y, b.z, b.w};
        ushort h[8], l[8];
        #pragma unroll
        for (int j = 0; j < 8; ++j) {
            h[j] = f2bf(v[j]);
            l[j] = f2bf(v[j] - bf2f(h[j]));
        }
        uint4 hv = make_uint4((uint)h[0] | ((uint)h[1] << 16),
                              (uint)h[2] | ((uint)h[3] << 16),
                              (uint)h[4] | ((uint)h[5] << 16),
                              (uint)h[6] | ((uint)h[7] << 16));
        uint4 lv = make_uint4((uint)l[0] | ((uint)l[1] << 16),
                              (uint)l[2] | ((uint)l[3] << 16),
                              (uint)l[4] | ((uint)l[5] << 16),
                              (uint)l[6] | ((uint)l[7] << 16));
        *(uint4*)(hi + i * 8) = hv;
        *(uint4*)(lo + i * 8) = lv;
    }
}

// ---------------------------------------------------------------------------
// bf16x3 split GEMM: C(MxN) = (Ah+Al)(M x K) @ ((Bh+Bl)(N x K))^T  (3 MFMA terms)
// 128x128 tile, 4 waves, BK=32. Staging: global_load_lds width=16, linear LDS
// dest, pre-swizzled global source chunk = (lane&3)^((lane>>2)&3) so that the
// XOR-swizzled LDS reader (identical to r7-verified) sees linear K.
// m204 bijective XCD swizzle on the linearized grid.
// ---------------------------------------------------------------------------
template<bool RELU, bool BIAS, bool ACCUM>
__global__ __launch_bounds__(256, 1)
void gemm_bf16x3(const ushort* __restrict__ Ah, const ushort* __restrict__ Al, int lda,
                 const ushort* __restrict__ Bh, const ushort* __restrict__ Bl, int ldb,
                 const float* __restrict__ bias, float* __restrict__ C, int ldc,
                 int M, int K)
{
    __shared__ __align__(16) ushort sAh[4096], sAl[4096], sBh[4096], sBl[4096];
    const int t = threadIdx.x;
    const int lane = t & 63, w = t >> 6;
    const int wr = (w >> 1) << 6, wc = (w & 1) << 6;

    // XCD-aware bijective remap (m204): consecutive remapped ids share an XCD
    // and (bid%gridDim.x fast) share the same B panel -> L2 reuse.
    const int nwg = gridDim.x * gridDim.y;
    int bid = blockIdx.x + blockIdx.y * gridDim.x;
    {
        int q = nwg >> 3, r = nwg & 7;
        int xcd = bid & 7, rank = bid >> 3;
        bid = (xcd < r ? xcd * (q + 1) : r * (q + 1) + (xcd - r) * q) + rank;
    }
    const int m0 = (bid % gridDim.x) << 7;
    const int n0 = (bid / gridDim.x) << 7;

    const int ln15 = lane & 15, kb = lane >> 4;

    // staging geometry: wave w, sub-iter q in {0,1} fills LDS slots
    // [w*128+q*64, +64) (16B slots). slot s -> row = s>>2, chunkpos = s&3.
    // source chunk = chunkpos ^ (row&3)  (row&3 == (lane>>2)&3).
    const int srow0  = (w << 5) + (lane >> 2);              // q=0 row in tile
    const int schunk = (lane & 3) ^ ((lane >> 2) & 3);      // pre-swizzled src
    const int ldsb0  = w << 11;                             // w*2048 bytes

    f32x4_t zero4 = {0.f, 0.f, 0.f, 0.f};
    f32x4_t acc[4][4];
    #pragma unroll
    for (int m = 0; m < 4; ++m)
        #pragma unroll
        for (int n = 0; n < 4; ++n) acc[m][n] = zero4;

    for (int k0 = 0; k0 < K; k0 += 32) {
        __syncthreads();                    // prior iter's LDS reads complete
        #pragma unroll
        for (int q = 0; q < 2; ++q) {
            int row = srow0 + (q << 4);
            long ko = (long)k0 + schunk * 8;
            long ao = (long)(m0 + row) * lda + ko;
            long bo = (long)(n0 + row) * ldb + ko;
            int lo = ldsb0 + (q << 10);
            gload16(Ah + ao, (char*)sAh + lo);
            gload16(Al + ao, (char*)sAl + lo);
            gload16(Bh + bo, (char*)sBh + lo);
            gload16(Bl + bo, (char*)sBl + lo);
        }
        __syncthreads();                    // vmcnt(0) drain + barrier

        // B-fragments for all 4 column tiles (32 VGPRs live) ...
        bf16x8_t bh[4], bl[4];
        #pragma unroll
        for (int n = 0; n < 4; ++n) {
            int row = wc + (n << 4) + ln15;
            int idx = (row << 5) + ((kb ^ (row & 3)) << 3);
            bh[n] = *(const bf16x8_t*)&sBh[idx];
            bl[n] = *(const bf16x8_t*)&sBl[idx];
        }
        // ... A-fragments per-m (8 VGPRs at a time)
        #pragma unroll
        for (int m = 0; m < 4; ++m) {
            int row = wr + (m << 4) + ln15;
            int idx = (row << 5) + ((kb ^ (row & 3)) << 3);
            bf16x8_t ahm = *(const bf16x8_t*)&sAh[idx];
            bf16x8_t alm = *(const bf16x8_t*)&sAl[idx];
            #pragma unroll
            for (int n = 0; n < 4; ++n) {
                acc[m][n] = __builtin_amdgcn_mfma_f32_16x16x32_bf16(alm, bh[n], acc[m][n], 0, 0, 0);
                acc[m][n] = __builtin_amdgcn_mfma_f32_16x16x32_bf16(ahm, bl[n], acc[m][n], 0, 0, 0);
                acc[m][n] = __builtin_amdgcn_mfma_f32_16x16x32_bf16(ahm, bh[n], acc[m][n], 0, 0, 0);
            }
        }
    }

    // D layout: row = kb*4 + reg, col = ln15 within each 16x16 fragment
    #pragma unroll
    for (int m = 0; m < 4; ++m) {
        #pragma unroll
        for (int r = 0; r < 4; ++r) {
            int gr = m0 + wr + (m << 4) + (kb << 2) + r;
            if (gr >= M) continue;
            #pragma unroll
            for (int n = 0; n < 4; ++n) {
                int gc = n0 + wc + (n << 4) + ln15;
                float v = acc[m][n][r];
                if (BIAS) v += bias[gc];
                if (RELU) v = fmaxf(v, 0.f);
                float* cp = C + (long)gr * ldc + gc;
                if (ACCUM) *cp += v; else *cp = v;
            }
        }
    }
}

// ---------------------------------------------------------------------------
// Batched small GEMM (pinv etc): C = c0*A + c1*(A@B or A@B^T)   [fp32]
// ---------------------------------------------------------------------------
template<bool TRANSB>
__global__ __launch_bounds__(256)
void bgemm(const float* A0, long aB, const float* B0, long bB,
           float* __restrict__ C0, long cB, int N, int K, float c0, float c1)
{
    __shared__ float As[64][36];
    __shared__ float Bs[32][68];
    const int t = threadIdx.x, tx = t & 15, ty = t >> 4;
    const int tx4 = tx * 4, ty4 = ty * 4;
    const int m0 = blockIdx.x * 64, n0 = blockIdx.y * 64;
    const float* A = A0 + blockIdx.z * aB;
    const float* B = B0 + blockIdx.z * bB;
    float* C = C0 + blockIdx.z * cB;
    float acc[4][4] = {};
    for (int k0 = 0; k0 < K; k0 += 32) {
        __syncthreads();
        #pragma unroll
        for (int qq = 0; qq < 2; ++qq) {
            int q4 = t + qq * 256;
            int r = q4 >> 3, c4 = (q4 & 7) << 2;
            *(float4*)&As[r][c4] = *(const float4*)(A + (long)(m0 + r) * K + k0 + c4);
        }
        if (!TRANSB) {
            #pragma unroll
            for (int qq = 0; qq < 2; ++qq) {
                int q4 = t + qq * 256;
                int r = q4 >> 4, c4 = (q4 & 15) << 2;
                *(float4*)&Bs[r][c4] = *(const float4*)(B + (long)(k0 + r) * N + n0 + c4);
            }
        } else {
            #pragma unroll
            for (int qq = 0; qq < 2; ++qq) {
                int q4 = t + qq * 256;
                int n = q4 >> 3, c4 = (q4 & 7) << 2;
                float4 bv = *(const float4*)(B + (long)(n0 + n) * K + k0 + c4);
                Bs[c4 + 0][n] = bv.x; Bs[c4 + 1][n] = bv.y;
                Bs[c4 + 2][n] = bv.z; Bs[c4 + 3][n] = bv.w;
            }
        }
        __syncthreads();
        #pragma unroll
        for (int kq = 0; kq < 32; kq += 4) {
            float4 a0 = *(const float4*)&As[ty4 + 0][kq];
            float4 a1 = *(const float4*)&As[ty4 + 1][kq];
            float4 a2 = *(const float4*)&As[ty4 + 2][kq];
            float4 a3 = *(const float4*)&As[ty4 + 3][kq];
            float4 b0 = *(const float4*)&Bs[kq + 0][tx4];
            float4 b1 = *(const float4*)&Bs[kq + 1][tx4];
            float4 b2 = *(const float4*)&Bs[kq + 2][tx4];
            float4 b3 = *(const float4*)&Bs[kq + 3][tx4];
            fma44(acc[0], a0, b0, b1, b2, b3);
            fma44(acc[1], a1, b0, b1, b2, b3);
            fma44(acc[2], a2, b0, b1, b2, b3);
            fma44(acc[3], a3, b0, b1, b2, b3);
        }
    }
    #pragma unroll
    for (int i = 0; i < 4; ++i) {
        #pragma unroll
        for (int j = 0; j < 4; ++j) {
            float val = c1 * acc[i][j];
            if (c0 != 0.f)
                val += c0 * A[(long)(m0 + ty4 + i) * K + (n0 + tx4 + j)];
            C[(long)(m0 + ty4 + i) * N + n0 + tx4 + j] = val;
        }
    }
}

// ---------------------------------------------------------------------------
// Flash-style fused softmax(scale * Q@K^T) @ V, 64x64 tiles, fp32.
// ---------------------------------------------------------------------------
template<bool PARTIAL>
__global__ __launch_bounds__(256)
void flash_kernel(const float* __restrict__ qb, long q_rs, long q_hs,
                  const float* __restrict__ kb, long k_rs, long k_hs,
                  const float* __restrict__ vb, long v_rs, long v_hs,
                  float* __restrict__ ob, long o_rs, long o_hs,
                  float* __restrict__ pm, float* __restrict__ pl,
                  float* __restrict__ pacc, int ktiles, float scale)
{
    __shared__ float qs[64][68];
    __shared__ float kps[64][68];
    __shared__ float vs[64][68];
    const int t = threadIdx.x, tx = t & 15, ty = t >> 4;
    const int tx4 = tx * 4, ty4 = ty * 4;
    const int qt = blockIdx.x, h = blockIdx.y, ch = blockIdx.z;

    const float* q = qb + (long)h * q_hs + (long)(qt * 64) * q_rs;
    const float* k = kb + (long)h * k_hs + (long)(ch * ktiles * 64) * k_rs;
    const float* v = vb + (long)h * v_hs + (long)(ch * ktiles * 64) * v_rs;

    for (int q4 = t; q4 < 1024; q4 += 256) {
        int r = q4 >> 4, c4 = (q4 & 15) << 2;
        float4 val = *(const float4*)(q + (long)r * q_rs + c4);
        val.x *= scale; val.y *= scale; val.z *= scale; val.w *= scale;
        *(float4*)&qs[r][c4] = val;
    }

    float m_r[4], l_r[4], acc[4][4];
    #pragma unroll
    for (int i = 0; i < 4; ++i) {
        m_r[i] = -3.0e30f; l_r[i] = 0.f;
        acc[i][0] = acc[i][1] = acc[i][2] = acc[i][3] = 0.f;
    }

    for (int kt = 0; kt < ktiles; ++kt) {
        __syncthreads();
        for (int q4 = t; q4 < 1024; q4 += 256) {
            int r = q4 >> 4, c4 = (q4 & 15) << 2;
            float4 kv = *(const float4*)(k + (long)(kt * 64 + r) * k_rs + c4);
            kps[c4 + 0][r] = kv.x; kps[c4 + 1][r] = kv.y;
            kps[c4 + 2][r] = kv.z; kps[c4 + 3][r] = kv.w;
            *(float4*)&vs[r][c4] = *(const float4*)(v + (long)(kt * 64 + r) * v_rs + c4);
        }
        __syncthreads();
        float s[4][4] = {};
        #pragma unroll
        for (int kk = 0; kk < 64; kk += 4) {
            float4 a0 = *(const float4*)&qs[ty4 + 0][kk];
            float4 a1 = *(const float4*)&qs[ty4 + 1][kk];
            float4 a2 = *(const float4*)&qs[ty4 + 2][kk];
            float4 a3 = *(const float4*)&qs[ty4 + 3][kk];
            float4 b0 = *(const float4*)&kps[kk + 0][tx4];
            float4 b1 = *(const float4*)&kps[kk + 1][tx4];
            float4 b2 = *(const float4*)&kps[kk + 2][tx4];
            float4 b3 = *(const float4*)&kps[kk + 3][tx4];
            fma44(s[0], a0, b0, b1, b2, b3);
            fma44(s[1], a1, b0, b1, b2, b3);
            fma44(s[2], a2, b0, b1, b2, b3);
            fma44(s[3], a3, b0, b1, b2, b3);
        }
        float p[4][4];
        #pragma unroll
        for (int i = 0; i < 4; ++i) {
            float rm = fmaxf(fmaxf(s[i][0], s[i][1]), fmaxf(s[i][2], s[i][3]));
            rm = fmaxf(rm, __shfl_xor(rm, 1));
            rm = fmaxf(rm, __shfl_xor(rm, 2));
            rm = fmaxf(rm, __shfl_xor(rm, 4));
            rm = fmaxf(rm, __shfl_xor(rm, 8));
            float mn = fmaxf(m_r[i], rm);
            float corr = __expf(m_r[i] - mn);
            m_r[i] = mn;
            float rs = 0.f;
            #pragma unroll
            for (int j = 0; j < 4; ++j) { p[i][j] = __expf(s[i][j] - mn); rs += p[i][j]; }
            rs += __shfl_xor(rs, 1);
            rs += __shfl_xor(rs, 2);
            rs += __shfl_xor(rs, 4);
            rs += __shfl_xor(rs, 8);
            l_r[i] = l_r[i] * corr + rs;
            acc[i][0] *= corr; acc[i][1] *= corr; acc[i][2] *= corr; acc[i][3] *= corr;
        }
        __syncthreads();
        #pragma unroll
        for (int i = 0; i < 4; ++i)
            *(float4*)&kps[ty4 + i][tx4] = make_float4(p[i][0], p[i][1], p[i][2], p[i][3]);
        __syncthreads();
        #pragma unroll
        for (int nn = 0; nn < 64; nn += 4) {
            float4 a0 = *(const float4*)&kps[ty4 + 0][nn];
            float4 a1 = *(const float4*)&kps[ty4 + 1][nn];
            float4 a2 = *(const float4*)&kps[ty4 + 2][nn];
            float4 a3 = *(const float4*)&kps[ty4 + 3][nn];
            float4 b0 = *(const float4*)&vs[nn + 0][tx4];
            float4 b1 = *(const float4*)&vs[nn + 1][tx4];
            float4 b2 = *(const float4*)&vs[nn + 2][tx4];
            float4 b3 = *(const float4*)&vs[nn + 3][tx4];
            fma44(acc[0], a0, b0, b1, b2, b3);
            fma44(acc[1], a1, b0, b1, b2, b3);
            fma44(acc[2], a2, b0, b1, b2, b3);
            fma44(acc[3], a3, b0, b1, b2, b3);
        }
    }

    if (PARTIAL) {
        const int pidx = (h * gridDim.x + qt) * gridDim.z + ch;
        if (tx == 0) {
            #pragma unroll
            for (int i = 0; i < 4; ++i) {
                pm[pidx * 64 + ty4 + i] = m_r[i];
                pl[pidx * 64 + ty4 + i] = l_r[i];
            }
        }
        #pragma unroll
        for (int i = 0; i < 4; ++i)
            *(float4*)&pacc[(long)pidx * 4096 + (ty4 + i) * 64 + tx4] =
                make_float4(acc[i][0], acc[i][1], acc[i][2], acc[i][3]);
    } else {
        float* o = ob + (long)h * o_hs + (long)(qt * 64) * o_rs;
        #pragma unroll
        for (int i = 0; i < 4; ++i) {
            float inv = 1.f / l_r[i];
            *(float4*)(o + (long)(ty4 + i) * o_rs + tx4) =
                make_float4(acc[i][0] * inv, acc[i][1] * inv, acc[i][2] * inv, acc[i][3] * inv);
        }
    }
}

__global__ __launch_bounds__(256)
void combine_a3v(const float* __restrict__ pm, const float* __restrict__ pl,
                 const float* __restrict__ pacc, float* __restrict__ out3)
{
    int e = blockIdx.x * 256 + threadIdx.x;
    int d = e & 63, i = (e >> 6) & 255, h = e >> 14;
    int qt = i >> 6, r = i & 63;
    int pbase = (h * 4 + qt) * NCHUNK;
    float M = -3.0e30f;
    for (int c = 0; c < NCHUNK; ++c) M = fmaxf(M, pm[(pbase + c) * 64 + r]);
    float L = 0.f, val = 0.f;
    for (int c = 0; c < NCHUNK; ++c) {
        float w = __expf(pm[(pbase + c) * 64 + r] - M);
        L += pl[(pbase + c) * 64 + r] * w;
        val += pacc[(long)(pbase + c) * 4096 + r * 64 + d] * w;
    }
    out3[e] = val / L;
}

// ---------------------------------------------------------------------------
// LayerNorm h -> padded bf16 hi/lo (rows < PADR zeroed). grid NPD, block 256.
// ---------------------------------------------------------------------------
__global__ __launch_bounds__(256)
void ln_pad_bf16(const float* __restrict__ hin, const float* __restrict__ g,
                 const float* __restrict__ b, ushort* __restrict__ xph,
                 ushort* __restrict__ xpl)
{
    int row = blockIdx.x, t = threadIdx.x;
    if (row < PADR) {
        ((uint*)xph)[row * 256 + t] = 0;
        ((uint*)xpl)[row * 256 + t] = 0;
        return;
    }
    const float* xr = hin + (long)(row - PADR) * 512;
    float2 v = *(const float2*)&xr[t * 2];
    float s1 = v.x + v.y, s2 = v.x * v.x + v.y * v.y;
    for (int mask = 1; mask < 64; mask <<= 1) {
        s1 += __shfl_xor(s1, mask);
        s2 += __shfl_xor(s2, mask);
    }
    __shared__ float red[8];
    if ((t & 63) == 0) { red[(t >> 6) * 2] = s1; red[(t >> 6) * 2 + 1] = s2; }
    __syncthreads();
    s1 = red[0] + red[2] + red[4] + red[6];
    s2 = red[1] + red[3] + red[5] + red[7];
    float mu = s1 * (1.f / 512.f);
    float var = s2 * (1.f / 512.f) - mu * mu;
    float rstd = rsqrtf(var + 1e-5f);
    float2 gg = *(const float2*)&g[t * 2];
    float2 bb = *(const float2*)&b[t * 2];
    float ox = (v.x - mu) * rstd * gg.x + bb.x;
    float oy = (v.y - mu) * rstd * gg.y + bb.y;
    ushort hx = f2bf(ox), hy = f2bf(oy);
    ushort lx = f2bf(ox - bf2f(hx)), ly = f2bf(oy - bf2f(hy));
    ((uint*)xph)[row * 256 + t] = (uint)hx | ((uint)hy << 16);
    ((uint*)xpl)[row * 256 + t] = (uint)lx | ((uint)ly << 16);
}

// landmarks: mean over 65-token chunks of q and k. grid 2048, block 128.
__global__ __launch_bounds__(128)
void landmarks(const float* __restrict__ qkv, float* __restrict__ ql, float* __restrict__ kl)
{
    int bidx = blockIdx.x;
    int h = bidx >> 8, i = bidx & 255;
    int t = threadIdx.x, d = t & 63, which = t >> 6;
    const float* src = qkv + (which ? 512 : 0) + h * 64 + d;
    long base = (long)(i * 65) * 1536;
    float s = 0.f;
    for (int j = 0; j < 65; ++j) s += src[base + (long)j * 1536];
    float* dst = which ? kl : ql;
    dst[((h << 8) + i) * 64 + d] = s * (1.f / 65.f);
}

__global__ __launch_bounds__(256)
void softmax_rows(float* __restrict__ x)
{
    __shared__ float red[4];
    int row = blockIdx.x, t = threadIdx.x;
    float v = x[(long)row * 256 + t];
    float m = v;
    for (int mask = 1; mask < 64; mask <<= 1) m = fmaxf(m, __shfl_xor(m, mask));
    if ((t & 63) == 0) red[t >> 6] = m;
    __syncthreads();
    m = fmaxf(fmaxf(red[0], red[1]), fmaxf(red[2], red[3]));
    float p = __expf(v - m);
    float s = p;
    for (int mask = 1; mask < 64; mask <<= 1) s += __shfl_xor(s, mask);
    __syncthreads();
    if ((t & 63) == 0) red[t >> 6] = s;
    __syncthreads();
    s = red[0] + red[1] + red[2] + red[3];
    x[(long)row * 256 + t] = p / s;
}

__global__ __launch_bounds__(256)
void rowcolmax(const float* __restrict__ a2, float* __restrict__ red16)
{
    int h = blockIdx.x, t = threadIdx.x;
    const float* A = a2 + (long)h * 65536;
    float cs = 0.f, rs = 0.f;
    for (int i = 0; i < 256; ++i) cs += fabsf(A[i * 256 + t]);
    for (int j = 0; j < 256; ++j) rs += fabsf(A[t * 256 + j]);
    for (int mask = 1; mask < 64; mask <<= 1) {
        cs = fmaxf(cs, __shfl_xor(cs, mask));
        rs = fmaxf(rs, __shfl_xor(rs, mask));
    }
    __shared__ float red[8];
    if ((t & 63) == 0) { red[t >> 6] = rs; red[4 + (t >> 6)] = cs; }
    __syncthreads();
    if (t == 0) {
        float mr = fmaxf(fmaxf(red[0], red[1]), fmaxf(red[2], red[3]));
        float mc = fmaxf(fmaxf(red[4], red[5]), fmaxf(red[6], red[7]));
        red16[h] = mr;
        red16[8 + h] = mc;
    }
}

__global__ void pinv_scale(const float* __restrict__ red16, float* __restrict__ scal)
{
    if (threadIdx.x == 0) {
        float mr = red16[0], mc = red16[8];
        for (int i = 1; i < 8; ++i) {
            mr = fmaxf(mr, red16[i]);
            mc = fmaxf(mc, red16[8 + i]);
        }
        scal[0] = 1.f / (mr * mc);
    }
}

__global__ __launch_bounds__(256)
void ztrans(const float* __restrict__ a2, const float* __restrict__ scal, float* __restrict__ z)
{
    __shared__ float tl[64][65];
    int h = blockIdx.y, t = threadIdx.x;
    const float* A = a2 + (long)h * 65536;
    float* Z = z + (long)h * 65536;
    float s = scal[0];
    int i0 = (blockIdx.x & 3) * 64, j0 = (blockIdx.x >> 2) * 64;
    for (int q = t; q < 4096; q += 256) {
        int r = q >> 6, c = q & 63;
        tl[r][c] = A[(i0 + r) * 256 + j0 + c];
    }
    __syncthreads();
    for (int q = t; q < 4096; q += 256) {
        int r = q >> 6, c = q & 63;
        Z[(j0 + r) * 256 + i0 + c] = tl[c][r] * s;
    }
}

__global__ __launch_bounds__(256)
void resconv(const float* __restrict__ qkv, const float* __restrict__ rw, float* __restrict__ attn)
{
    int n = PADR + blockIdx.x;
    int c = blockIdx.y * 256 + threadIdx.x;
    int h = c >> 6;
    float s = 0.f;
    #pragma unroll
    for (int tt = 0; tt < 33; ++tt) {
        int m = n + tt - 16;
        if (m >= 0 && m < NPD) s += qkv[(long)m * 1536 + 1024 + c] * rw[h * 33 + tt];
    }
    attn[(long)n * 512 + c] += s;
}

__global__ void cls_copy(const float* __restrict__ cls, float* __restrict__ h)
{
    h[threadIdx.x] = cls[threadIdx.x];
}

__global__ __launch_bounds__(256)
void transpose_nc_cn(const float* __restrict__ h, float* __restrict__ f)
{
    __shared__ float tl[32][33];
    int p0 = blockIdx.x * 32, c0 = blockIdx.y * 32;
    int txx = threadIdx.x & 31, tyy = threadIdx.x >> 5;
    #pragma unroll
    for (int k = 0; k < 4; ++k) {
        int r = tyy * 4 + k;
        tl[r][txx] = h[(long)(1 + p0 + r) * 512 + c0 + txx];
    }
    __syncthreads();
    #pragma unroll
    for (int k = 0; k < 4; ++k) {
        int r = tyy * 4 + k;
        f[(long)(c0 + r) * 16384 + p0 + txx] = tl[txx][r];
    }
}

__global__ __launch_bounds__(256)
void transpose_cn_nc(const float* __restrict__ g, float* __restrict__ h)
{
    __shared__ float tl[32][33];
    int p0 = blockIdx.x * 32, c0 = blockIdx.y * 32;
    int txx = threadIdx.x & 31, tyy = threadIdx.x >> 5;
    #pragma unroll
    for (int k = 0; k < 4; ++k) {
        int r = tyy * 4 + k;
        tl[r][txx] = g[(long)(c0 + r) * 16384 + p0 + txx];
    }
    __syncthreads();
    #pragma unroll
    for (int k = 0; k < 4; ++k) {
        int r = tyy * 4 + k;
        h[(long)(1 + p0 + r) * 512 + c0 + txx] = tl[txx][r];
    }
}

__global__ __launch_bounds__(128)
void ppeg_conv(const float* __restrict__ fin, float* __restrict__ fout,
               const float* __restrict__ w7, const float* __restrict__ b7,
               const float* __restrict__ w5, const float* __restrict__ b5,
               const float* __restrict__ w3, const float* __restrict__ b3)
{
    int y = blockIdx.x, c = blockIdx.y;
    int x = threadIdx.x;
    __shared__ float ld[7][134];
    const float* base = fin + (long)c * 16384;
    #pragma unroll
    for (int ry = 0; ry < 7; ++ry) {
        int row = y + ry - 3;
        ld[ry][3 + x] = (row >= 0 && row < 128) ? base[row * 128 + x] : 0.f;
    }
    if (x < 3) {
        #pragma unroll
        for (int ry = 0; ry < 7; ++ry) { ld[ry][x] = 0.f; ld[ry][131 + x] = 0.f; }
    }
    __syncthreads();
    float acc = ld[3][3 + x] + b7[c] + b5[c] + b3[c];
    #pragma unroll
    for (int dy = 0; dy < 7; ++dy)
        #pragma unroll
        for (int dx = 0; dx < 7; ++dx)
            acc += ld[dy][x + dx] * w7[c * 49 + dy * 7 + dx];
    #pragma unroll
    for (int dy = 0; dy < 5; ++dy)
        #pragma unroll
        for (int dx = 0; dx < 5; ++dx)
            acc += ld[dy + 1][x + 1 + dx] * w5[c * 25 + dy * 5 + dx];
    #pragma unroll
    for (int dy = 0; dy < 3; ++dy)
        #pragma unroll
        for (int dx = 0; dx < 3; ++dx)
            acc += ld[dy + 2][x + 2 + dx] * w3[c * 9 + dy * 3 + dx];
    fout[(long)c * 16384 + y * 128 + x] = acc;
}

__global__ __launch_bounds__(256)
void final_head(const float* __restrict__ h, const float* __restrict__ g,
                const float* __restrict__ bb, const float* __restrict__ w,
                const float* __restrict__ bias, float* __restrict__ out)
{
    __shared__ float red[8];
    int t = threadIdx.x;
    float2 v = *(const float2*)&h[t * 2];
    float s1 = v.x + v.y, s2 = v.x * v.x + v.y * v.y;
    for (int mask = 1; mask < 64; mask <<= 1) {
        s1 += __shfl_xor(s1, mask);
        s2 += __shfl_xor(s2, mask);
    }
    if ((t & 63) == 0) { red[t >> 6] = s1; red[4 + (t >> 6)] = s2; }
    __syncthreads();
    s1 = red[0] + red[1] + red[2] + red[3];
    s2 = red[4] + red[5] + red[6] + red[7];
    float mu = s1 * (1.f / 512.f);
    float var = s2 * (1.f / 512.f) - mu * mu;
    float rstd = rsqrtf(var + 1e-5f);
    float2 gg = *(const float2*)&g[t * 2];
    float2 b2v = *(const float2*)&bb[t * 2];
    float o0 = (v.x - mu) * rstd * gg.x + b2v.x;
    float o1 = (v.y - mu) * rstd * gg.y + b2v.y;
    float p0 = o0 * w[t * 2] + o1 * w[t * 2 + 1];
    float p1 = o0 * w[512 + t * 2] + o1 * w[512 + t * 2 + 1];
    for (int mask = 1; mask < 64; mask <<= 1) {
        p0 += __shfl_xor(p0, mask);
        p1 += __shfl_xor(p1, mask);
    }
    __syncthreads();
    if ((t & 63) == 0) { red[t >> 6] = p0; red[4 + (t >> 6)] = p1; }
    __syncthreads();
    if (t == 0) {
        out[0] = red[0] + red[1] + red[2] + red[3] + bias[0];
        out[1] = red[4] + red[5] + red[6] + red[7] + bias[1];
    }
}

// ---------------------------------------------------------------------------
static void run_nystrom(hipStream_t stream, float* h, ushort* xph, ushort* xpl,
                        float* qkv, float* attn, float* ql, float* kl, float* a2b,
                        float* zA, float* zB, float* xzb, float* u1b, float* u2b,
                        float* out3, float* wvb, float* pm, float* pl, float* pacc,
                        float* red16, float* scal,
                        const float* ng, const float* nb,
                        const ushort* qwh, const ushort* qwl,
                        const ushort* owh, const ushort* owl,
                        const float* ob, const float* resw)
{
    ln_pad_bf16<<<NPD, 256, 0, stream>>>(h, ng, nb, xph, xpl);
    gemm_bf16x3<false, false, false><<<dim3(130, 12), 256, 0, stream>>>(
        xph, xpl, 512, qwh, qwl, 512, nullptr, qkv, 1536, NPD, 512);
    landmarks<<<2048, 128, 0, stream>>>(qkv, ql, kl);
    bgemm<true><<<dim3(4, 4, 8), 256, 0, stream>>>(ql, 16384L, kl, 16384L, a2b, 65536L,
                                                   256, 64, 0.f, SCL);
    softmax_rows<<<2048, 256, 0, stream>>>(a2b);
    rowcolmax<<<8, 256, 0, stream>>>(a2b, red16);
    pinv_scale<<<1, 64, 0, stream>>>(red16, scal);
    ztrans<<<dim3(16, 8), 256, 0, stream>>>(a2b, scal, zA);
    float* zc = zA;
    float* zn = zB;
    for (int it = 0; it < 6; ++it) {
        bgemm<false><<<dim3(4, 4, 8), 256, 0, stream>>>(a2b, 65536L, zc, 65536L, xzb, 65536L,
                                                        256, 256, 0.f, 1.f);
        bgemm<false><<<dim3(4, 4, 8), 256, 0, stream>>>(xzb, 65536L, xzb, 65536L, u1b, 65536L,
                                                        256, 256, 7.f, -1.f);
        bgemm<false><<<dim3(4, 4, 8), 256, 0, stream>>>(xzb, 65536L, u1b, 65536L, u2b, 65536L,
                                                        256, 256, 15.f, -1.f);
        bgemm<false><<<dim3(4, 4, 8), 256, 0, stream>>>(zc, 65536L, u2b, 65536L, zn, 65536L,
                                                        256, 256, 3.25f, -0.25f);
        float* tmp = zc; zc = zn; zn = tmp;
    }
    flash_kernel<true><<<dim3(4, 8, NCHUNK), 256, 0, stream>>>(
        ql, 64L, 16384L, qkv + 512, 1536L, 64L, qkv + 1024, 1536L, 64L,
        nullptr, 0L, 0L, pm, pl, pacc, KT_A3, SCL);
    combine_a3v<<<512, 256, 0, stream>>>(pm, pl, pacc, out3);
    bgemm<false><<<dim3(4, 1, 8), 256, 0, stream>>>(zc, 65536L, out3, 16384L, wvb, 16384L,
                                                    64, 256, 0.f, 1.f);
    flash_kernel<false><<<dim3(260, 8, 1), 256, 0, stream>>>(
        qkv, 1536L, 64L, kl, 64L, 16384L, wvb, 64L, 16384L,
        attn, 512L, 64L, nullptr, nullptr, nullptr, 4, SCL);
    resconv<<<dim3(16385, 2), 256, 0, stream>>>(qkv, resw, attn);
    // convert attn rows [PADR, PADR+NTOK) to bf16 hi/lo (reuse xp region)
    cvt_split<<<2048, 256, 0, stream>>>(attn + (long)PADR * 512, xph, xpl,
                                        (long)NTOK * 512 / 8);
    // h += attn_bf16 @ ow^T + ob
    gemm_bf16x3<false, true, true><<<dim3(129, 4), 256, 0, stream>>>(
        xph, xpl, 512, owh, owl, 512, ob, h, 512, NTOK, 512);
}

extern "C" void kernel_launch(void* const* d_in, const int* in_sizes, int n_in,
                              void* d_out, int out_size, void* d_ws, size_t ws_size,
                              hipStream_t stream)
{
    const float* x      = (const float*)d_in[0];
    const float* fc1w   = (const float*)d_in[1];
    const float* fc1b   = (const float*)d_in[2];
    const float* clstok = (const float*)d_in[3];
    const float* l1ng   = (const float*)d_in[4];
    const float* l1nb   = (const float*)d_in[5];
    const float* l1qkv  = (const float*)d_in[6];
    const float* l1ow   = (const float*)d_in[7];
    const float* l1ob   = (const float*)d_in[8];
    const float* l1res  = (const float*)d_in[9];
    const float* pw7    = (const float*)d_in[10];
    const float* pb7    = (const float*)d_in[11];
    const float* pw5    = (const float*)d_in[12];
    const float* pb5    = (const float*)d_in[13];
    const float* pw3    = (const float*)d_in[14];
    const float* pb3    = (const float*)d_in[15];
    const float* l2ng   = (const float*)d_in[16];
    const float* l2nb   = (const float*)d_in[17];
    const float* l2qkv  = (const float*)d_in[18];
    const float* l2ow   = (const float*)d_in[19];
    const float* l2ob   = (const float*)d_in[20];
    const float* l2res  = (const float*)d_in[21];
    const float* fng    = (const float*)d_in[22];
    const float* fnb    = (const float*)d_in[23];
    const float* fc2w   = (const float*)d_in[24];
    const float* fc2b   = (const float*)d_in[25];
    (void)in_sizes; (void)n_in; (void)out_size; (void)ws_size;
    float* out = (float*)d_out;
    float* ws = (float*)d_ws;

    size_t off = 0;
    auto alloc = [&](size_t n) { float* p = ws + off; off += n; return p; };
    float* h    = alloc((size_t)NTOK * 512);
    float* xph_f = alloc((size_t)NPD * 256);      // NPD*512 ushorts
    float* xpl_f = alloc((size_t)NPD * 256);
    float* qkv  = alloc((size_t)NPD * 1536);
    float* attn = alloc((size_t)NPD * 512);
    float* ql   = alloc(8 * 256 * 64);
    float* kl   = alloc(8 * 256 * 64);
    float* a2b  = alloc(8 * 256 * 256);
    float* zA   = alloc(8 * 256 * 256);
    float* zB   = alloc(8 * 256 * 256);
    float* xzb  = alloc(8 * 256 * 256);
    float* u1b  = alloc(8 * 256 * 256);
    float* u2b  = alloc(8 * 256 * 256);
    float* out3 = alloc(8 * 256 * 64);
    float* wvb  = alloc(8 * 256 * 64);
    float* pm   = alloc(8 * 4 * NCHUNK * 64);
    float* pl   = alloc(8 * 4 * NCHUNK * 64);
    float* pacc = alloc((size_t)8 * 4 * NCHUNK * 4096);
    float* red16 = alloc(16);
    float* scal  = alloc(4);
    // bf16 weight buffers (ushort counts halved into float words)
    ushort* fwh = (ushort*)alloc(512 * 1024 / 2);
    ushort* fwl = (ushort*)alloc(512 * 1024 / 2);
    ushort* q1h = (ushort*)alloc(1536 * 512 / 2);
    ushort* q1l = (ushort*)alloc(1536 * 512 / 2);
    ushort* q2h = (ushort*)alloc(1536 * 512 / 2);
    ushort* q2l = (ushort*)alloc(1536 * 512 / 2);
    ushort* o1h = (ushort*)alloc(512 * 512 / 2);
    ushort* o1l = (ushort*)alloc(512 * 512 / 2);
    ushort* o2h = (ushort*)alloc(512 * 512 / 2);
    ushort* o2l = (ushort*)alloc(512 * 512 / 2);

    ushort* xph = (ushort*)xph_f;
    ushort* xpl = (ushort*)xpl_f;
    // x hi/lo aliases the (not yet written) qkv region: 2*8.39M floats <= 25.5M
    ushort* xh = (ushort*)qkv;
    ushort* xl = (ushort*)(qkv + (size_t)16384 * 1024 / 2);
    float* fbuf = qkv;                      // PPEG reuses the (dead) qkv region
    float* gbuf = qkv + (size_t)NPD * 512;

    // weight conversions
    cvt_split<<<256, 256, 0, stream>>>(fc1w, fwh, fwl, 512 * 1024 / 8);
    cvt_split<<<384, 256, 0, stream>>>(l1qkv, q1h, q1l, 1536 * 512 / 8);
    cvt_split<<<384, 256, 0, stream>>>(l2qkv, q2h, q2l, 1536 * 512 / 8);
    cvt_split<<<128, 256, 0, stream>>>(l1ow, o1h, o1l, 512 * 512 / 8);
    cvt_split<<<128, 256, 0, stream>>>(l2ow, o2h, o2l, 512 * 512 / 8);
    cvt_split<<<2048, 256, 0, stream>>>(x, xh, xl, (long)16384 * 1024 / 8);

    // h[1:] = relu(x @ fc1_w^T + fc1_b); h[0] = cls_token
    gemm_bf16x3<true, true, false><<<dim3(128, 4), 256, 0, stream>>>(
        xh, xl, 1024, fwh, fwl, 1024, fc1b, h + 512, 512, 16384, 1024);
    cls_copy<<<1, 512, 0, stream>>>(clstok, h);

    run_nystrom(stream, h, xph, xpl, qkv, attn, ql, kl, a2b, zA, zB, xzb, u1b, u2b,
                out3, wvb, pm, pl, pacc, red16, scal,
                l1ng, l1nb, q1h, q1l, o1h, o1l, l1ob, l1res);

    transpose_nc_cn<<<dim3(512, 16), 256, 0, stream>>>(h, fbuf);
    ppeg_conv<<<dim3(128, 512), 128, 0, stream>>>(fbuf, gbuf, pw7, pb7, pw5, pb5, pw3, pb3);
    transpose_cn_nc<<<dim3(512, 16), 256, 0, stream>>>(gbuf, h);

    run_nystrom(stream, h, xph, xpl, qkv, attn, ql, kl, a2b, zA, zB, xzb, u1b, u2b,
                out3, wvb, pm, pl, pacc, red16, scal,
                l2ng, l2nb, q2h, q2l, o2h, o2l, l2ob, l2res);

    final_head<<<1, 256, 0, stream>>>(h, fng, fnb, fc2w, fc2b, out);
}